// Round 7
// baseline (292.354 us; speedup 1.0000x reference)
//
#include <hip/hip_runtime.h>
#include <hip/hip_bf16.h>

// Problem constants (T,K,E,H,I) = (1024, 2, 8, 2048, 1024)
#define T_TOK 1024
#define KSEL  2
#define NEXP  8
#define HDIM  2048
#define IDIM  1024
#define TK    2048            // (token, slot) pairs; sum of expert counts == TK

#define BR 72                 // LDS B-tile row stride in bf16 elems (64 payload + 8 pad)

typedef float  f32x4  __attribute__((ext_vector_type(4)));
typedef __bf16 bf16x8 __attribute__((ext_vector_type(8)));
typedef __bf16 bf16x2 __attribute__((ext_vector_type(2)));

__device__ __forceinline__ unsigned short f2bf(float f) {
    union { float f; unsigned u; } v; v.f = f;
    unsigned r = (v.u >> 16) & 1u;               // round-to-nearest-even
    return (unsigned short)((v.u + 0x7fffu + r) >> 16);
}

__device__ __forceinline__ unsigned pk2bf(float lo, float hi) {
#if __has_builtin(__builtin_amdgcn_cvt_pk_bf16_f32)
    bf16x2 v = __builtin_amdgcn_cvt_pk_bf16_f32(lo, hi);
    union { bf16x2 v; unsigned u; } c; c.v = v;
    return c.u;
#else
    return (unsigned)f2bf(lo) | ((unsigned)f2bf(hi) << 16);
#endif
}

// ---------------------------------------------------------------------------
// Kernel 1: prep = hidden fp32->bf16 (all blocks) + expert counting-sort
// (block 0 only). Grid 1024 x 256 covers T*H/8 = 262144 chunks exactly.
// ---------------------------------------------------------------------------
__global__ __launch_bounds__(256) void prep(
    const float* __restrict__ hidden, const int* __restrict__ sel,
    unsigned short* __restrict__ hid_bf, int* __restrict__ meta,
    int* __restrict__ pairs)
{
    const int t = blockIdx.x * 256 + threadIdx.x;
    {
        const float* s = hidden + (size_t)t * 8;
        float4 v0 = *(const float4*)s;
        float4 v1 = *(const float4*)(s + 4);
        uint4 o;
        o.x = pk2bf(v0.x, v0.y); o.y = pk2bf(v0.z, v0.w);
        o.z = pk2bf(v1.x, v1.y); o.w = pk2bf(v1.z, v1.w);
        *(uint4*)(hid_bf + (size_t)t * 8) = o;
    }
    if (blockIdx.x == 0) {
        __shared__ int lcnt[NEXP], lstart[NEXP], lfill[NEXP];
        const int tid = threadIdx.x;
        if (tid < NEXP) { lcnt[tid] = 0; lfill[tid] = 0; }
        __syncthreads();
        for (int i = tid; i < TK; i += 256) atomicAdd(&lcnt[sel[i]], 1);
        __syncthreads();
        if (tid == 0) {
            int s2 = 0;
            for (int e2 = 0; e2 < NEXP; ++e2) { lstart[e2] = s2; s2 += lcnt[e2]; }
        }
        __syncthreads();
        for (int i = tid; i < TK; i += 256) {
            int e2 = sel[i];
            pairs[lstart[e2] + atomicAdd(&lfill[e2], 1)] = i;   // i == t*K+k
        }
        if (tid < NEXP) { meta[tid] = lcnt[tid]; meta[NEXP + tid] = lstart[tid]; }
    }
}

// ---------------------------------------------------------------------------
// Kernel 2: gate_up GEMM + SiLU*up -> bf16 inter (packed rows).
// Block = 256 thr = 4 waves; wave w owns M rows [48w, 48w+48) -> 192 rows.
// N = 32 inter cols (64 weight rows: 32 gate + 32 up). B fp32 -> cvt in-reg
// -> LDS (triple-buffer, 2-slab reg prefetch). A direct from global
// (XCD-local L2; e=bx&7 pins expert->XCD). K-slab 64, NK=32.
// Grid mt(2) x nt(32) x e(8) = 512 blocks = 2/CU: the second resident block
// computes through the first block's vmcnt(0)-before-barrier drain (m114).
// ---------------------------------------------------------------------------
__global__ __launch_bounds__(256, 2) void gemm1_gateup(
    const unsigned short* __restrict__ hid_bf, const float* __restrict__ gup,
    const int* __restrict__ meta, const int* __restrict__ pairs,
    unsigned short* __restrict__ inter)
{
    __shared__ __align__(16) unsigned short Bs[3][64 * BR];

    const int bx = blockIdx.x;
    const int e = bx & 7, nt = (bx >> 3) & 31, mt = bx >> 8;
    const int cnt = meta[e];
    const int m0 = mt * 192;
    if (m0 >= cnt) return;
    const int seg  = meta[8 + e];
    const int rows = cnt - m0;            // valid rows in this tile
    const int n0   = nt * 32;

    const int tid  = threadIdx.x;
    const int lane = tid & 63, w = tid >> 6;        // w in [0,4)
    const int quad = lane >> 4, l16 = lane & 15;

    // B staging map (256 thr): thread = weight-row (tid>>2), k-chunk (tid&3)*16.
    const int brow = tid >> 2, bkc = (tid & 3) * 16;
    const int grow = (brow < 32) ? (n0 + brow) : (IDIM + n0 + (brow - 32));
    const float* __restrict__ bp =
        gup + (size_t)e * (2 * IDIM * HDIM) + (size_t)grow * HDIM + bkc;
    const int bofs = brow * BR + bkc;

    // A fragment base pointers: 3 m-tiles of 16 rows, lane row = l16.
    const unsigned short* ap[3];
    #pragma unroll
    for (int i = 0; i < 3; ++i) {
        int mr  = m0 + w * 48 + i * 16 + l16;
        int idx = seg + min(mr, cnt - 1);          // clamp (dup rows masked later)
        ap[i] = hid_bf + (size_t)(pairs[idx] >> 1) * HDIM + quad * 8;
    }

    f32x4 accg[3][2], accu[3][2];
    const f32x4 zero = {0.f, 0.f, 0.f, 0.f};
    #pragma unroll
    for (int i = 0; i < 3; ++i)
        #pragma unroll
        for (int j = 0; j < 2; ++j) { accg[i][j] = zero; accu[i][j] = zero; }

    float4 Br0[4], Br1[4];
    bf16x8 afA[3][2], afB[3][2];

    auto loadB = [&](float4 (&br)[4], int s) {
        const float* p = bp + s * 64;
        #pragma unroll
        for (int c = 0; c < 4; ++c) br[c] = *(const float4*)(p + c * 4);
    };
    auto storeB = [&](const float4 (&br)[4], int buf) {
        uint4 o0, o1;
        o0.x = pk2bf(br[0].x, br[0].y); o0.y = pk2bf(br[0].z, br[0].w);
        o0.z = pk2bf(br[1].x, br[1].y); o0.w = pk2bf(br[1].z, br[1].w);
        o1.x = pk2bf(br[2].x, br[2].y); o1.y = pk2bf(br[2].z, br[2].w);
        o1.z = pk2bf(br[3].x, br[3].y); o1.w = pk2bf(br[3].z, br[3].w);
        *(uint4*)&Bs[buf][bofs]     = o0;
        *(uint4*)&Bs[buf][bofs + 8] = o1;
    };
    auto loadA = [&](bf16x8 (&af)[3][2], int s) {
        #pragma unroll
        for (int i = 0; i < 3; ++i)
            #pragma unroll
            for (int kk = 0; kk < 2; ++kk)
                af[i][kk] = *(const bf16x8*)(ap[i] + s * 64 + kk * 32);
    };
    auto compute = [&](const bf16x8 (&af)[3][2], int buf) {
        #pragma unroll
        for (int kk = 0; kk < 2; ++kk) {
            const int ko = kk * 32 + quad * 8;
            bf16x8 bg[2], bu[2];
            #pragma unroll
            for (int j = 0; j < 2; ++j) {
                bg[j] = *(const bf16x8*)&Bs[buf][(j * 16 + l16) * BR + ko];
                bu[j] = *(const bf16x8*)&Bs[buf][(32 + j * 16 + l16) * BR + ko];
            }
            #pragma unroll
            for (int i = 0; i < 3; ++i)
                #pragma unroll
                for (int j = 0; j < 2; ++j) {
                    accg[i][j] = __builtin_amdgcn_mfma_f32_16x16x32_bf16(af[i][kk], bg[j], accg[i][j], 0, 0, 0);
                    accu[i][j] = __builtin_amdgcn_mfma_f32_16x16x32_bf16(af[i][kk], bu[j], accu[i][j], 0, 0, 0);
                }
        }
    };

    const int NK = HDIM / 64;   // 32
    loadB(Br0, 0);
    loadA(afA, 0);
    storeB(Br0, 0);
    loadB(Br0, 1);
    loadB(Br1, 2);
    __syncthreads();

    for (int s = 0; s < NK; s += 2) {
        // even half: Bs[s%3]=slab s ready; Br0=raw s+1, Br1=raw s+2
        storeB(Br0, (s + 1) % 3);
        if (s + 3 < NK) loadB(Br0, s + 3);
        loadA(afB, s + 1);
        compute(afA, s % 3);
        __syncthreads();
        // odd half
        if (s + 2 < NK) storeB(Br1, (s + 2) % 3);
        if (s + 4 < NK) loadB(Br1, s + 4);
        if (s + 2 < NK) loadA(afA, s + 2);
        compute(afB, (s + 1) % 3);
        __syncthreads();
    }

    // Epilogue: silu(gate)*up -> inter (packed rows, bf16).
    #pragma unroll
    for (int i = 0; i < 3; ++i) {
        #pragma unroll
        for (int r = 0; r < 4; ++r) {
            int mrow = w * 48 + i * 16 + quad * 4 + r;
            if (mrow < rows && mrow < 192) {
                size_t orow = (size_t)(seg + m0 + mrow) * IDIM;
                #pragma unroll
                for (int j = 0; j < 2; ++j) {
                    float g = accg[i][j][r], u = accu[i][j][r];
                    float sv = g * (1.f / (1.f + __expf(-g)));
                    inter[orow + n0 + j * 16 + l16] = f2bf(sv * u);
                }
            }
        }
    }
}

// ---------------------------------------------------------------------------
// Kernel 3: down-proj GEMM. 256 thr = 4 waves, M 192 x N 64, B = 64 down rows
// fp32 streamed (XCD-L2-shared across the 2 mt-blocks), A = inter from L2.
// K-slab 64, NK=16. Grid mt(2) x nt(32) x e(8) = 512 = 2/CU.
// Output fp32 scattered to out[pairs[p]].
// ---------------------------------------------------------------------------
__global__ __launch_bounds__(256, 2) void gemm2_down(
    const unsigned short* __restrict__ inter, const float* __restrict__ down,
    const int* __restrict__ meta, const int* __restrict__ pairs,
    float* __restrict__ out)
{
    __shared__ __align__(16) unsigned short Bs[3][64 * BR];

    const int bx = blockIdx.x;
    const int e = bx & 7, nt = (bx >> 3) & 31, mt = bx >> 8;
    const int cnt = meta[e];
    const int m0 = mt * 192;
    if (m0 >= cnt) return;
    const int seg  = meta[8 + e];
    const int rows = cnt - m0;
    const int n0   = nt * 64;

    const int tid  = threadIdx.x;
    const int lane = tid & 63, w = tid >> 6;
    const int quad = lane >> 4, l16 = lane & 15;

    const int brow = tid >> 2, bkc = (tid & 3) * 16;
    const float* __restrict__ bp =
        down + (size_t)e * (HDIM * IDIM) + (size_t)(n0 + brow) * IDIM + bkc;
    const int bofs = brow * BR + bkc;

    const unsigned short* ap[3];
    #pragma unroll
    for (int i = 0; i < 3; ++i) {
        int mr  = m0 + w * 48 + i * 16 + l16;
        int idx = seg + min(mr, cnt - 1);
        ap[i] = inter + (size_t)idx * IDIM + quad * 8;
    }

    f32x4 acc[3][4];
    const f32x4 zero = {0.f, 0.f, 0.f, 0.f};
    #pragma unroll
    for (int i = 0; i < 3; ++i)
        #pragma unroll
        for (int j = 0; j < 4; ++j) acc[i][j] = zero;

    float4 Br0[4], Br1[4];
    bf16x8 afA[3][2], afB[3][2];

    auto loadB = [&](float4 (&br)[4], int s) {
        const float* p = bp + s * 64;
        #pragma unroll
        for (int c = 0; c < 4; ++c) br[c] = *(const float4*)(p + c * 4);
    };
    auto storeB = [&](const float4 (&br)[4], int buf) {
        uint4 o0, o1;
        o0.x = pk2bf(br[0].x, br[0].y); o0.y = pk2bf(br[0].z, br[0].w);
        o0.z = pk2bf(br[1].x, br[1].y); o0.w = pk2bf(br[1].z, br[1].w);
        o1.x = pk2bf(br[2].x, br[2].y); o1.y = pk2bf(br[2].z, br[2].w);
        o1.z = pk2bf(br[3].x, br[3].y); o1.w = pk2bf(br[3].z, br[3].w);
        *(uint4*)&Bs[buf][bofs]     = o0;
        *(uint4*)&Bs[buf][bofs + 8] = o1;
    };
    auto loadA = [&](bf16x8 (&af)[3][2], int s) {
        #pragma unroll
        for (int i = 0; i < 3; ++i)
            #pragma unroll
            for (int kk = 0; kk < 2; ++kk)
                af[i][kk] = *(const bf16x8*)(ap[i] + s * 64 + kk * 32);
    };
    auto compute = [&](const bf16x8 (&af)[3][2], int buf) {
        #pragma unroll
        for (int kk = 0; kk < 2; ++kk) {
            const int ko = kk * 32 + quad * 8;
            bf16x8 bf[4];
            #pragma unroll
            for (int j = 0; j < 4; ++j)
                bf[j] = *(const bf16x8*)&Bs[buf][(j * 16 + l16) * BR + ko];
            #pragma unroll
            for (int i = 0; i < 3; ++i)
                #pragma unroll
                for (int j = 0; j < 4; ++j)
                    acc[i][j] = __builtin_amdgcn_mfma_f32_16x16x32_bf16(af[i][kk], bf[j], acc[i][j], 0, 0, 0);
        }
    };

    const int NK = IDIM / 64;   // 16
    loadB(Br0, 0);
    loadA(afA, 0);
    storeB(Br0, 0);
    loadB(Br0, 1);
    loadB(Br1, 2);
    __syncthreads();

    for (int s = 0; s < NK; s += 2) {
        storeB(Br0, (s + 1) % 3);
        if (s + 3 < NK) loadB(Br0, s + 3);
        loadA(afB, s + 1);
        compute(afA, s % 3);
        __syncthreads();
        if (s + 2 < NK) storeB(Br1, (s + 2) % 3);
        if (s + 4 < NK) loadB(Br1, s + 4);
        if (s + 2 < NK) loadA(afA, s + 2);
        compute(afB, (s + 1) % 3);
        __syncthreads();
    }

    #pragma unroll
    for (int i = 0; i < 3; ++i) {
        #pragma unroll
        for (int r = 0; r < 4; ++r) {
            int mrow = w * 48 + i * 16 + quad * 4 + r;
            if (mrow < rows && mrow < 192) {
                int p = pairs[seg + m0 + mrow];          // == t*K+k = out row
                size_t ob = (size_t)p * HDIM + n0 + l16;
                #pragma unroll
                for (int j = 0; j < 4; ++j)
                    out[ob + j * 16] = acc[i][j][r];
            }
        }
    }
}

// ---------------------------------------------------------------------------
extern "C" void kernel_launch(void* const* d_in, const int* in_sizes, int n_in,
                              void* d_out, int out_size, void* d_ws, size_t ws_size,
                              hipStream_t stream) {
    const float* hidden = (const float*)d_in[0];   // (T, H) fp32
    const int*   sel    = (const int*)  d_in[1];   // (T, K) int32
    const float* gup    = (const float*)d_in[2];   // (E, 2I, H) fp32
    const float* down   = (const float*)d_in[3];   // (E, H, I) fp32
    float* out = (float*)d_out;                    // (T, K, H) fp32

    // ws: meta 16 ints | pairs 2048 ints | inter bf16 2048x1024 (4 MB)
    //     | hid_bf bf16 1024x2048 (4 MB)   -- total ~8.1 MB
    char* ws = (char*)d_ws;
    int* meta  = (int*)ws;
    int* pairs = meta + 16;
    unsigned short* inter  = (unsigned short*)(ws + 16384);
    unsigned short* hid_bf = inter + (size_t)TK * IDIM;

    prep<<<T_TOK * HDIM / 8 / 256, 256, 0, stream>>>(hidden, sel, hid_bf, meta, pairs);
    gemm1_gateup<<<2 * 32 * 8, 256, 0, stream>>>(hid_bf, gup, meta, pairs, inter);
    gemm2_down  <<<2 * 32 * 8, 256, 0, stream>>>(inter, down, meta, pairs, out);
}